// Round 17
// baseline (80.575 us; speedup 1.0000x reference)
//
#include <hip/hip_runtime.h>
#include <math.h>

#define IMW 512
#define IMH 512
#define NPIX (IMW * IMH)
#define NBX 8
#define NBY 8
#define NBLK (NBX * NBY * 96)
#define C1F 1.0e-4f
#define C2F 9.0e-4f
#define H2P2 20         // H2 pitch in words per (q,col) row

typedef short s16x8 __attribute__((ext_vector_type(8)));
typedef float f32x4 __attribute__((ext_vector_type(4)));
typedef float f32x2 __attribute__((ext_vector_type(2)));

// ---- helpers ----
__device__ __forceinline__ unsigned cvtpk(float a, float b) {   // lo=bf16(a), hi=bf16(b), RNE
    unsigned r;
    asm("v_cvt_pk_bf16_f32 %0, %1, %2" : "=v"(r) : "v"(a), "v"(b));
    return r;
}
__device__ __forceinline__ unsigned bf16_rne(float f) {
    unsigned u = __builtin_bit_cast(unsigned, f);
    return (u + 0x7FFFu + ((u >> 16) & 1u)) >> 16;
}
__device__ __forceinline__ float bf16_to_f(unsigned b) {
    return __builtin_bit_cast(float, b << 16);
}
__device__ __forceinline__ f32x4 spl4(float v) { f32x4 r = {v, v, v, v}; return r; }
__device__ __forceinline__ f32x2 spl2(float v) { f32x2 r; r[0] = v; r[1] = v; return r; }
__device__ __forceinline__ f32x2 lo2(f32x4 v) { f32x2 r; r[0] = v[0]; r[1] = v[1]; return r; }
__device__ __forceinline__ f32x2 hi2(f32x4 v) { f32x2 r; r[0] = v[2]; r[1] = v[3]; return r; }

// packed fp32 (VOP3P). gfx950 has NO v_pk_max_f32; abs is scalar and-mask.
__device__ __forceinline__ f32x2 pk_mul(f32x2 a, f32x2 b) {
    f32x2 d; asm("v_pk_mul_f32 %0, %1, %2" : "=v"(d) : "v"(a), "v"(b)); return d;
}
__device__ __forceinline__ f32x2 pk_add(f32x2 a, f32x2 b) {
    f32x2 d; asm("v_pk_add_f32 %0, %1, %2" : "=v"(d) : "v"(a), "v"(b)); return d;
}
__device__ __forceinline__ f32x2 pk_sub(f32x2 a, f32x2 b) {
    f32x2 d; asm("v_pk_add_f32 %0, %1, %2 neg_lo:[0,1] neg_hi:[0,1]" : "=v"(d) : "v"(a), "v"(b)); return d;
}
__device__ __forceinline__ f32x2 pk_fma(f32x2 a, f32x2 b, f32x2 c) {
    f32x2 d; asm("v_pk_fma_f32 %0, %1, %2, %3" : "=v"(d) : "v"(a), "v"(b), "v"(c)); return d;
}
__device__ __forceinline__ f32x2 abs2(f32x2 a) {
    f32x2 d; d[0] = fabsf(a[0]); d[1] = fabsf(a[1]); return d;
}

// ---- setup: build per-lane MFMA weight fragments once (block-invariant) ----
__global__ void setup_kernel(uint4* __restrict__ wtab)
{
    const int lane = threadIdx.x;        // 0..63
    const int lane15 = lane & 15;
    const int g = lane >> 4;
    float w[11];
    float s = 0.f;
    for (int i = 0; i < 11; ++i) {
        const float c = (float)(i - 5);
        w[i] = expf(-(c * c) / 4.5f);
        s += w[i];
    }
    for (int i = 0; i < 11; ++i) w[i] /= s;

    s16x8 bwh, bwl, avh, avl;
    #pragma unroll
    for (int e = 0; e < 8; ++e) {
        const int k = 8 * g + e;
        // h-pass B (32x16): B[k][n] = w[k-n-3]  (slot origin c0-8; out col n = c0+16wv+n)
        const int th = k - lane15 - 3;
        const float wh = (th >= 0 && th <= 10) ? w[th] : 0.f;
        // v-pass A (16x32): A[i][k'] = w[k'-i]
        const int tv = k - lane15;
        const float wvv = (tv >= 0 && tv <= 10) ? w[tv] : 0.f;
        const unsigned h1 = bf16_rne(wh);
        const unsigned l1 = bf16_rne(wh - bf16_to_f(h1));
        bwh[e] = (short)h1; bwl[e] = (short)l1;
        const unsigned h2 = bf16_rne(wvv);
        const unsigned l2 = bf16_rne(wvv - bf16_to_f(h2));
        avh[e] = (short)h2; avl[e] = (short)l2;
    }
    wtab[lane * 4 + 0] = __builtin_bit_cast(uint4, bwh);
    wtab[lane * 4 + 1] = __builtin_bit_cast(uint4, bwl);
    wtab[lane * 4 + 2] = __builtin_bit_cast(uint4, avh);
    wtab[lane * 4 + 3] = __builtin_bit_cast(uint4, avl);
}

__global__ __launch_bounds__(256)
void ssim_l1_kernel(const float* __restrict__ warped,
                    const float* __restrict__ target,
                    const uint4* __restrict__ wtab,
                    float2* __restrict__ partial)
{
    // NO staging LDS, NO mid-kernel barriers: each lane loads its h-pass
    // A-fragment window (2x16B of x and y) directly from global, prefetch
    // distance 2 in registers. LDS holds only H2 (rolling 2-slot, wave-private)
    // and the 8-word reduction tail.
    __shared__ unsigned int LDSU[5128];   // 20512 B

    const int tid = threadIdx.x;
    const int lane = tid & 63;
    const int wv = tid >> 6;
    const int lane15 = lane & 15;
    const int g = (lane >> 4) & 3;
    const int c0 = blockIdx.x * 64;
    const int r0 = blockIdx.y * 64;
    const size_t base = (size_t)blockIdx.z * NPIX;

    const char* xc = (const char*)(warped + base);
    const char* yc = (const char*)(target + base);

    // ---- weight fragments ----
    const s16x8 BwH = __builtin_bit_cast(s16x8, wtab[lane * 4 + 0]);
    const s16x8 BwL = __builtin_bit_cast(s16x8, wtab[lane * 4 + 1]);
    const s16x8 AvH = __builtin_bit_cast(s16x8, wtab[lane * 4 + 2]);
    const s16x8 AvL = __builtin_bit_cast(s16x8, wtab[lane * 4 + 3]);

    // ---- per-lane load addressing (clamped; clamp-garbage zeroed by edge masks) ----
    const int s0 = 16 * wv + 8 * g;                 // first slot of this lane's window
    const int cb0 = (c0 - 8) * 4;
    const int colb = min(max(cb0 + s0 * 4, 0), 2016);   // byte col of 32B window, in-row

    // ---- masks ----
    f32x4 cw0, cw1, mx0, mx1;
    #pragma unroll
    for (int e = 0; e < 4; ++e) {
        const int sA = s0 + e, sB = sA + 4;
        cw0[e] = (sA < 8 || sA > 71) ? 0.f : ((sA < 16 || sA >= 64) ? 1.f : 0.5f);
        cw1[e] = (sB < 8 || sB > 71) ? 0.f : ((sB < 16 || sB >= 64) ? 1.f : 0.5f);
        const int cA = c0 - 8 + sA, cB = c0 - 8 + sB;
        mx0[e] = ((unsigned)cA < (unsigned)IMW) ? 1.f : 0.f;
        mx1[e] = ((unsigned)cB < (unsigned)IMW) ? 1.f : 0.f;
    }
    const f32x2 cw0lo = lo2(cw0), cw0hi = hi2(cw0);
    const f32x2 cw1lo = lo2(cw1), cw1hi = hi2(cw1);
    // edge if clamped loads or out-of-image rows/cols possible
    const bool edge = (blockIdx.x == 0) || (blockIdx.x == NBX - 1) ||
                      (blockIdx.y == 0) || (blockIdx.y == NBY - 1) ||
                      (colb != cb0 + s0 * 4);

    f32x2 l1a = spl2(0.f), l1b = spl2(0.f);
    f32x2 ssa = spl2(0.f), ssb = spl2(0.f);
    const f32x2 two2 = spl2(2.f), c12 = spl2(C1F), c22 = spl2(C2F);

    // v-pass read offsets (hoisted): uoff selects rolling H2 slots by tile parity
    const int uoffE = 4 * g;                             // even ot
    const int uoffO = 8 - 8 * (g >> 1) + 4 * (g & 1);    // odd ot

    auto VPASS = [&](int ot) {
        const int uoff = (ot & 1) ? uoffO : uoffE;
        f32x4 V[4];
        __builtin_amdgcn_s_setprio(1);
        #pragma unroll
        for (int q = 0; q < 4; ++q) {
            const uint4 br = *(const uint4*)&LDSU[((wv * 4 + q) * 16 + lane15) * H2P2 + uoff];
            const s16x8 B = __builtin_bit_cast(s16x8, br);
            f32x4 acc = spl4(0.f);
            acc = __builtin_amdgcn_mfma_f32_16x16x32_bf16(AvH, B, acc, 0, 0, 0);
            acc = __builtin_amdgcn_mfma_f32_16x16x32_bf16(AvL, B, acc, 0, 0, 0);
            V[q] = acc;
        }
        __builtin_amdgcn_s_setprio(0);
        #pragma unroll
        for (int h = 0; h < 2; ++h) {
            const f32x2 v0 = h ? hi2(V[0]) : lo2(V[0]);
            const f32x2 v1 = h ? hi2(V[1]) : lo2(V[1]);
            const f32x2 v2 = h ? hi2(V[2]) : lo2(V[2]);
            const f32x2 v3 = h ? hi2(V[3]) : lo2(V[3]);
            const f32x2 mu12  = pk_mul(v0, v1);
            const f32x2 mu1sq = pk_mul(v0, v0);
            const f32x2 mu2sq = pk_mul(v1, v1);
            const f32x2 s12   = pk_sub(v3, mu12);
            const f32x2 ssg   = pk_sub(pk_sub(v2, mu1sq), mu2sq);   // sigma1^2 + sigma2^2
            const f32x2 num = pk_mul(pk_fma(two2, mu12, c12), pk_fma(two2, s12, c22));
            const f32x2 den = pk_mul(pk_add(pk_add(mu1sq, mu2sq), c12), pk_add(ssg, c22));
            f32x2 r;
            r[0] = __builtin_amdgcn_rcpf(den[0]);
            r[1] = __builtin_amdgcn_rcpf(den[1]);
            if (h) ssb = pk_fma(num, r, ssb);
            else   ssa = pk_fma(num, r, ssa);
        }
    };

    // ---- register prefetch buffers (statically indexed via full unroll) ----
    f32x4 P0[4], P1[4];
    auto LOADB = [&](int t, f32x4* dst) {
        const int rsl = min(max(r0 - 5 + 16 * t + lane15, 0), IMH - 1);
        const char* px = xc + (size_t)rsl * (IMW * 4) + colb;
        const char* py = yc + (size_t)rsl * (IMW * 4) + colb;
        dst[0] = *(const f32x4*)px;
        dst[1] = *(const f32x4*)(px + 16);
        dst[2] = *(const f32x4*)py;
        dst[3] = *(const f32x4*)(py + 16);
    };

    LOADB(0, P0);
    LOADB(1, P1);

    // ---- barrier-free loop over 5 bands; v-pass of tile t-1 fused into band t ----
    #pragma unroll
    for (int t = 0; t < 5; ++t) {
        f32x4* B = (t & 1) ? P1 : P0;    // static after unroll
        f32x4 x0 = B[0], x1 = B[1], y0 = B[2], y1 = B[3];
        if (t + 2 < 5) LOADB(t + 2, B);  // refill same buffer; flies under 2 bands of compute

        if (edge) {
            // zero-pad: out-of-image rows AND cols (exact SAME-padding semantics)
            const float rr = ((unsigned)(r0 - 5 + 16 * t + lane15) < (unsigned)IMH) ? 1.f : 0.f;
            const f32x4 m0 = mx0 * spl4(rr);
            const f32x4 m1 = mx1 * spl4(rr);
            x0 *= m0; x1 *= m1; y0 *= m0; y1 *= m1;
        }

        // L1 (exact f32; output rows = slots 5..68, each counted once) — packed
        {
            const float rmL1 = (t == 0) ? ((lane15 >= 5) ? 1.f : 0.f)
                             : (t == 4) ? ((lane15 <= 4) ? 1.f : 0.f)
                             : 1.f;
            const f32x2 rm2 = spl2(rmL1);
            const f32x2 t0 = abs2(pk_sub(lo2(x0), lo2(y0)));
            const f32x2 t1 = abs2(pk_sub(hi2(x0), hi2(y0)));
            const f32x2 t2 = abs2(pk_sub(lo2(x1), lo2(y1)));
            const f32x2 t3 = abs2(pk_sub(hi2(x1), hi2(y1)));
            const f32x2 s01 = pk_fma(cw0lo, t0, pk_mul(cw1lo, t2));
            const f32x2 s23 = pk_fma(cw0hi, t1, pk_mul(cw1hi, t3));
            l1a = pk_fma(s01, rm2, l1a);
            l1b = pk_fma(s23, rm2, l1b);
        }

        // quantity products — packed
        const f32x2 q2al = pk_fma(lo2(x0), lo2(x0), pk_mul(lo2(y0), lo2(y0)));
        const f32x2 q2ah = pk_fma(hi2(x0), hi2(x0), pk_mul(hi2(y0), hi2(y0)));
        const f32x2 q2bl = pk_fma(lo2(x1), lo2(x1), pk_mul(lo2(y1), lo2(y1)));
        const f32x2 q2bh = pk_fma(hi2(x1), hi2(x1), pk_mul(hi2(y1), hi2(y1)));
        const f32x2 q3al = pk_mul(lo2(x0), lo2(y0));
        const f32x2 q3ah = pk_mul(hi2(x0), hi2(y0));
        const f32x2 q3bl = pk_mul(lo2(x1), lo2(y1));
        const f32x2 q3bh = pk_mul(hi2(x1), hi2(y1));

        uint4 A0u, A1u, A2u, A3u;
        A0u.x = cvtpk(x0[0], x0[1]); A0u.y = cvtpk(x0[2], x0[3]);
        A0u.z = cvtpk(x1[0], x1[1]); A0u.w = cvtpk(x1[2], x1[3]);
        A1u.x = cvtpk(y0[0], y0[1]); A1u.y = cvtpk(y0[2], y0[3]);
        A1u.z = cvtpk(y1[0], y1[1]); A1u.w = cvtpk(y1[2], y1[3]);
        A2u.x = cvtpk(q2al[0], q2al[1]); A2u.y = cvtpk(q2ah[0], q2ah[1]);
        A2u.z = cvtpk(q2bl[0], q2bl[1]); A2u.w = cvtpk(q2bh[0], q2bh[1]);
        A3u.x = cvtpk(q3al[0], q3al[1]); A3u.y = cvtpk(q3ah[0], q3ah[1]);
        A3u.z = cvtpk(q3bl[0], q3bl[1]); A3u.w = cvtpk(q3bh[0], q3bh[1]);

        const s16x8 A0 = __builtin_bit_cast(s16x8, A0u);
        const s16x8 A1 = __builtin_bit_cast(s16x8, A1u);
        const s16x8 A2 = __builtin_bit_cast(s16x8, A2u);
        const s16x8 A3 = __builtin_bit_cast(s16x8, A3u);

        f32x4 C0 = spl4(0.f), C1 = spl4(0.f), C2 = spl4(0.f), C3 = spl4(0.f);
        __builtin_amdgcn_s_setprio(1);
        C0 = __builtin_amdgcn_mfma_f32_16x16x32_bf16(A0, BwH, C0, 0, 0, 0);
        C0 = __builtin_amdgcn_mfma_f32_16x16x32_bf16(A0, BwL, C0, 0, 0, 0);
        C1 = __builtin_amdgcn_mfma_f32_16x16x32_bf16(A1, BwH, C1, 0, 0, 0);
        C1 = __builtin_amdgcn_mfma_f32_16x16x32_bf16(A1, BwL, C1, 0, 0, 0);
        C2 = __builtin_amdgcn_mfma_f32_16x16x32_bf16(A2, BwH, C2, 0, 0, 0);
        C2 = __builtin_amdgcn_mfma_f32_16x16x32_bf16(A2, BwL, C2, 0, 0, 0);
        C3 = __builtin_amdgcn_mfma_f32_16x16x32_bf16(A3, BwH, C3, 0, 0, 0);
        C3 = __builtin_amdgcn_mfma_f32_16x16x32_bf16(A3, BwL, C3, 0, 0, 0);
        __builtin_amdgcn_s_setprio(0);

        // repack band t into rolling H2 slot (t&1)  [wave-private]
        #pragma unroll
        for (int q = 0; q < 4; ++q) {
            const f32x4 Cq = (q == 0) ? C0 : (q == 1) ? C1 : (q == 2) ? C2 : C3;
            uint2 pp;
            pp.x = cvtpk(Cq[0], Cq[1]);
            pp.y = cvtpk(Cq[2], Cq[3]);
            *(uint2*)&LDSU[((wv * 4 + q) * 16 + lane15) * H2P2 + (t & 1) * 8 + 2 * g] = pp;
        }

        // v-pass for output tile t-1 (needs bands t-1 and t) [wave-private]
        if (t >= 1) VPASS(t - 1);
    }

    // ---- reductions ----
    float l1sum = (l1a[0] + l1a[1]) + (l1b[0] + l1b[1]);
    float ssum  = (ssa[0] + ssa[1]) + (ssb[0] + ssb[1]);
    #pragma unroll
    for (int off = 32; off > 0; off >>= 1) {
        l1sum += __shfl_down(l1sum, off);
        ssum  += __shfl_down(ssum,  off);
    }
    float* red = (float*)&LDSU[5120];
    if (lane == 0) { red[wv] = l1sum; red[4 + wv] = ssum; }
    __syncthreads();
    if (tid == 0) {
        const float L1 = red[0] + red[1] + red[2] + red[3];
        const float SS = red[4] + red[5] + red[6] + red[7];
        const int bid = (blockIdx.z * gridDim.y + blockIdx.y) * gridDim.x + blockIdx.x;
        partial[bid] = make_float2(L1, SS);
    }
}

__global__ __launch_bounds__(256)
void reduce_kernel(const float2* __restrict__ partial, float* __restrict__ out)
{
    double l1 = 0.0, ss = 0.0;
    for (int i = threadIdx.x; i < NBLK; i += 256) {
        const float2 p = partial[i];
        l1 += (double)p.x;
        ss += (double)p.y;
    }
    #pragma unroll
    for (int off = 32; off > 0; off >>= 1) {
        l1 += __shfl_down(l1, off);
        ss += __shfl_down(ss, off);
    }
    __shared__ double red[8];
    const int wv = threadIdx.x >> 6, lane = threadIdx.x & 63;
    if (lane == 0) { red[wv] = l1; red[4 + wv] = ss; }
    __syncthreads();
    if (threadIdx.x == 0) {
        const double n = 25165824.0;   // 32*3*512*512
        const double L1 = (red[0] + red[1] + red[2] + red[3]) / n;
        const double SS = (red[4] + red[5] + red[6] + red[7]) / n;
        out[0] = (float)(0.5 * L1 + 0.5 * (1.0 - SS));
    }
}

extern "C" void kernel_launch(void* const* d_in, const int* in_sizes, int n_in,
                              void* d_out, int out_size, void* d_ws, size_t ws_size,
                              hipStream_t stream)
{
    const float* warped = (const float*)d_in[0];
    const float* target = (const float*)d_in[1];
    float* out = (float*)d_out;
    uint4* wtab = (uint4*)d_ws;                            // 4 KB fragment table
    float2* partial = (float2*)((char*)d_ws + 4096);       // NBLK float2 partials

    hipLaunchKernelGGL(setup_kernel, dim3(1), dim3(64), 0, stream, wtab);
    hipLaunchKernelGGL(ssim_l1_kernel, dim3(NBX, NBY, 96), dim3(256), 0, stream,
                       warped, target, wtab, partial);
    hipLaunchKernelGGL(reduce_kernel, dim3(1), dim3(256), 0, stream, partial, out);
}

// Round 18
// 78.069 us; speedup vs baseline: 1.0321x; 1.0321x over previous
//
#include <hip/hip_runtime.h>
#include <math.h>

#define IMW 512
#define IMH 512
#define NPIX (IMW * IMH)
#define NBX 8
#define NBY 8
#define NBLK (NBX * NBY * 96)
#define C1F 1.0e-4f
#define C2F 9.0e-4f
#define H2B 8192        // H2 base (words); staging occupies words [0, 8192)
#define H2P2 20         // H2 pitch in words per (q,col) row

typedef short s16x8 __attribute__((ext_vector_type(8)));
typedef float f32x4 __attribute__((ext_vector_type(4)));
typedef float f32x2 __attribute__((ext_vector_type(2)));

// ---- helpers ----
__device__ __forceinline__ unsigned cvtpk(float a, float b) {   // lo=bf16(a), hi=bf16(b), RNE
    unsigned r;
    asm("v_cvt_pk_bf16_f32 %0, %1, %2" : "=v"(r) : "v"(a), "v"(b));
    return r;
}
__device__ __forceinline__ unsigned bf16_rne(float f) {
    unsigned u = __builtin_bit_cast(unsigned, f);
    return (u + 0x7FFFu + ((u >> 16) & 1u)) >> 16;
}
__device__ __forceinline__ float bf16_to_f(unsigned b) {
    return __builtin_bit_cast(float, b << 16);
}
__device__ __forceinline__ void gload16(const void* g, void* l) {
    __builtin_amdgcn_global_load_lds(
        (const __attribute__((address_space(1))) void*)g,
        (__attribute__((address_space(3))) void*)l,
        16, 0, 0);
}
__device__ __forceinline__ f32x4 spl4(float v) { f32x4 r = {v, v, v, v}; return r; }
__device__ __forceinline__ f32x2 spl2(float v) { f32x2 r; r[0] = v; r[1] = v; return r; }
__device__ __forceinline__ f32x2 lo2(f32x4 v) { f32x2 r; r[0] = v[0]; r[1] = v[1]; return r; }
__device__ __forceinline__ f32x2 hi2(f32x4 v) { f32x2 r; r[0] = v[2]; r[1] = v[3]; return r; }

// packed fp32 (VOP3P). gfx950 has NO v_pk_max_f32; abs is scalar and-mask.
__device__ __forceinline__ f32x2 pk_mul(f32x2 a, f32x2 b) {
    f32x2 d; asm("v_pk_mul_f32 %0, %1, %2" : "=v"(d) : "v"(a), "v"(b)); return d;
}
__device__ __forceinline__ f32x2 pk_add(f32x2 a, f32x2 b) {
    f32x2 d; asm("v_pk_add_f32 %0, %1, %2" : "=v"(d) : "v"(a), "v"(b)); return d;
}
__device__ __forceinline__ f32x2 pk_sub(f32x2 a, f32x2 b) {
    f32x2 d; asm("v_pk_add_f32 %0, %1, %2 neg_lo:[0,1] neg_hi:[0,1]" : "=v"(d) : "v"(a), "v"(b)); return d;
}
__device__ __forceinline__ f32x2 pk_fma(f32x2 a, f32x2 b, f32x2 c) {
    f32x2 d; asm("v_pk_fma_f32 %0, %1, %2, %3" : "=v"(d) : "v"(a), "v"(b), "v"(c)); return d;
}
__device__ __forceinline__ f32x2 abs2(f32x2 a) {
    f32x2 d; d[0] = fabsf(a[0]); d[1] = fabsf(a[1]); return d;
}

// ---- setup: build per-lane MFMA weight fragments once (block-invariant) ----
__global__ void setup_kernel(uint4* __restrict__ wtab)
{
    const int lane = threadIdx.x;        // 0..63
    const int lane15 = lane & 15;
    const int g = lane >> 4;
    float w[11];
    float s = 0.f;
    for (int i = 0; i < 11; ++i) {
        const float c = (float)(i - 5);
        w[i] = expf(-(c * c) / 4.5f);
        s += w[i];
    }
    for (int i = 0; i < 11; ++i) w[i] /= s;

    s16x8 bwh, bwl, avh, avl;
    #pragma unroll
    for (int e = 0; e < 8; ++e) {
        const int k = 8 * g + e;
        // h-pass B (32x16): B[k][n] = w[k-n-3]  (window origin = wave col base - 8)
        const int th = k - lane15 - 3;
        const float wh = (th >= 0 && th <= 10) ? w[th] : 0.f;
        // v-pass A (16x32): A[i][k'] = w[k'-i]
        const int tv = k - lane15;
        const float wvv = (tv >= 0 && tv <= 10) ? w[tv] : 0.f;
        const unsigned h1 = bf16_rne(wh);
        const unsigned l1 = bf16_rne(wh - bf16_to_f(h1));
        bwh[e] = (short)h1; bwl[e] = (short)l1;
        const unsigned h2 = bf16_rne(wvv);
        const unsigned l2 = bf16_rne(wvv - bf16_to_f(h2));
        avh[e] = (short)h2; avl[e] = (short)l2;
    }
    wtab[lane * 4 + 0] = __builtin_bit_cast(uint4, bwh);
    wtab[lane * 4 + 1] = __builtin_bit_cast(uint4, bwl);
    wtab[lane * 4 + 2] = __builtin_bit_cast(uint4, avh);
    wtab[lane * 4 + 3] = __builtin_bit_cast(uint4, avl);
}

__global__ __launch_bounds__(256)
void ssim_l1_kernel(const float* __restrict__ warped,
                    const float* __restrict__ target,
                    const uint4* __restrict__ wtab,
                    float2* __restrict__ partial)
{
    // WAVE-PRIVATE staging via global_load_lds: wave wv owns bytes [wv*8192, wv*8192+8192):
    //   buffer b (0/1) at +b*4096; x at +0, y at +2048; row pitch 128 B (16 rows);
    //   16B granules XOR-swizzled by (row&7) on the SOURCE address (rule 21).
    // NO cross-wave barriers: RAW via counted per-wave vmcnt, WAR via lgkmcnt(0).
    // H2 (rolling 2-slot repack) at words [H2B, H2B+5120); red at word 13312.
    __shared__ unsigned int LDSU[13320];   // 53280 B -> 3 blocks/CU

    const int tid = threadIdx.x;
    const int lane = tid & 63;
    const int wv = tid >> 6;
    const int lane15 = lane & 15;
    const int g = (lane >> 4) & 3;
    const int c0 = blockIdx.x * 64;
    const int r0 = blockIdx.y * 64;
    const size_t base = (size_t)blockIdx.z * NPIX;
    char* LB = (char*)LDSU;
    char* SB = LB + wv * 8192;             // this wave's staging area

    const char* xc = (const char*)(warped + base);
    const char* yc = (const char*)(target + base);

    // ---- weight fragments ----
    const s16x8 BwH = __builtin_bit_cast(s16x8, wtab[lane * 4 + 0]);
    const s16x8 BwL = __builtin_bit_cast(s16x8, wtab[lane * 4 + 1]);
    const s16x8 AvH = __builtin_bit_cast(s16x8, wtab[lane * 4 + 2]);
    const s16x8 AvL = __builtin_bit_cast(s16x8, wtab[lane * 4 + 3]);

    // ---- staging descriptors (band-invariant, hoisted) ----
    // granule idx0 = lane (rows 0..7), idx1 = lane+64 (rows 8..15); 8 granules/row
    const int wcb0 = (c0 - 8 + 16 * wv) * 4;            // byte col of wave window start
    const int row0 = lane >> 3;                          // 0..7
    const int row1 = row0 + 8;                           // 8..15
    const int gl   = lane & 7;
    const int scol0 = min(max(wcb0 + ((gl ^ (row0 & 7)) << 4), 0), 2032);
    const int scol1 = min(max(wcb0 + ((gl ^ (row1 & 7)) << 4), 0), 2032);
    const int lo0 = lane * 16;
    const int lo1 = lane * 16 + 1024;

    auto STAGE = [&](int t, int b) {
        const int rbase = r0 - 5 + 16 * t;
        const size_t rb0 = (size_t)min(max(rbase + row0, 0), IMH - 1) * 2048;
        const size_t rb1 = (size_t)min(max(rbase + row1, 0), IMH - 1) * 2048;
        char* db = SB + b * 4096;
        gload16(xc + rb0 + scol0, db + lo0);
        gload16(xc + rb1 + scol1, db + lo1);
        gload16(yc + rb0 + scol0, db + 2048 + lo0);
        gload16(yc + rb1 + scol1, db + 2048 + lo1);
    };

    // ---- h-pass read addressing (swizzled) ----
    const unsigned roff = (unsigned)(lane15 * 128);
    const unsigned gA = (unsigned)((((2 * g)    ) ^ (lane15 & 7)) * 16);
    const unsigned gB = (unsigned)((((2 * g) + 1) ^ (lane15 & 7)) * 16);

    // ---- masks ----
    const int s0 = 16 * wv + 8 * g;                 // first abs slot of this lane's frag
    f32x4 cw0, cw1, mx0, mx1;
    #pragma unroll
    for (int e = 0; e < 4; ++e) {
        const int sA = s0 + e, sB2 = sA + 4;
        cw0[e] = (sA < 8 || sA > 71) ? 0.f : ((sA < 16 || sA >= 64) ? 1.f : 0.5f);
        cw1[e] = (sB2 < 8 || sB2 > 71) ? 0.f : ((sB2 < 16 || sB2 >= 64) ? 1.f : 0.5f);
        const int cA = c0 - 8 + sA, cB = c0 - 8 + sB2;
        mx0[e] = ((unsigned)cA < (unsigned)IMW) ? 1.f : 0.f;
        mx1[e] = ((unsigned)cB < (unsigned)IMW) ? 1.f : 0.f;
    }
    const f32x2 cw0lo = lo2(cw0), cw0hi = hi2(cw0);
    const f32x2 cw1lo = lo2(cw1), cw1hi = hi2(cw1);
    const bool edge = (blockIdx.x == 0) || (blockIdx.x == NBX - 1) ||
                      (blockIdx.y == 0) || (blockIdx.y == NBY - 1);

    f32x2 l1a = spl2(0.f), l1b = spl2(0.f);
    f32x2 ssa = spl2(0.f), ssb = spl2(0.f);
    const f32x2 two2 = spl2(2.f), c12 = spl2(C1F), c22 = spl2(C2F);

    // v-pass read offsets: uoff selects rolling H2 slots by tile parity
    const int uoffE = 4 * g;                             // even ot
    const int uoffO = 8 - 8 * (g >> 1) + 4 * (g & 1);    // odd ot

    auto VPASS = [&](int ot) {
        const int uoff = (ot & 1) ? uoffO : uoffE;
        f32x4 V[4];
        __builtin_amdgcn_s_setprio(1);
        #pragma unroll
        for (int q = 0; q < 4; ++q) {
            const uint4 br = *(const uint4*)&LDSU[H2B + ((wv * 4 + q) * 16 + lane15) * H2P2 + uoff];
            const s16x8 B = __builtin_bit_cast(s16x8, br);
            f32x4 acc = spl4(0.f);
            acc = __builtin_amdgcn_mfma_f32_16x16x32_bf16(AvH, B, acc, 0, 0, 0);
            acc = __builtin_amdgcn_mfma_f32_16x16x32_bf16(AvL, B, acc, 0, 0, 0);
            V[q] = acc;
        }
        __builtin_amdgcn_s_setprio(0);
        #pragma unroll
        for (int h = 0; h < 2; ++h) {
            const f32x2 v0 = h ? hi2(V[0]) : lo2(V[0]);
            const f32x2 v1 = h ? hi2(V[1]) : lo2(V[1]);
            const f32x2 v2 = h ? hi2(V[2]) : lo2(V[2]);
            const f32x2 v3 = h ? hi2(V[3]) : lo2(V[3]);
            const f32x2 mu12  = pk_mul(v0, v1);
            const f32x2 mu1sq = pk_mul(v0, v0);
            const f32x2 mu2sq = pk_mul(v1, v1);
            const f32x2 s12   = pk_sub(v3, mu12);
            const f32x2 ssg   = pk_sub(pk_sub(v2, mu1sq), mu2sq);   // sigma1^2 + sigma2^2
            const f32x2 num = pk_mul(pk_fma(two2, mu12, c12), pk_fma(two2, s12, c22));
            const f32x2 den = pk_mul(pk_add(pk_add(mu1sq, mu2sq), c12), pk_add(ssg, c22));
            f32x2 r;
            r[0] = __builtin_amdgcn_rcpf(den[0]);
            r[1] = __builtin_amdgcn_rcpf(den[1]);
            if (h) ssb = pk_fma(num, r, ssb);
            else   ssa = pk_fma(num, r, ssa);
        }
    };

    // ---- prologue: stage bands 0 and 1 (wave-private, distance 2) ----
    STAGE(0, 0);
    STAGE(1, 1);
    __builtin_amdgcn_sched_barrier(0);

    // ---- barrier-free pipelined loop over 5 bands ----
    #pragma unroll
    for (int t = 0; t < 5; ++t) {
        // RAW: wait for band t's 4 loads; band t+1's stay in flight (counted, never 0 mid-loop)
        if (t < 4) asm volatile("s_waitcnt vmcnt(4)" ::: "memory");
        else       asm volatile("s_waitcnt vmcnt(0)" ::: "memory");

        const char* pb = SB + (t & 1) * 4096;
        f32x4 x0 = *(const f32x4*)(pb + roff + gA);
        f32x4 x1 = *(const f32x4*)(pb + roff + gB);
        f32x4 y0 = *(const f32x4*)(pb + 2048 + roff + gA);
        f32x4 y1 = *(const f32x4*)(pb + 2048 + roff + gB);

        // WAR: reads must land before re-staging this buffer (gload bypasses DS-pipe order)
        asm volatile("s_waitcnt lgkmcnt(0)" ::: "memory");
        __builtin_amdgcn_sched_barrier(0);
        if (t + 2 <= 4) {
            STAGE(t + 2, t & 1);
            __builtin_amdgcn_sched_barrier(0);
        }

        if (edge) {
            // zero-pad: out-of-image rows AND cols (exact SAME-padding semantics)
            const float rr = ((unsigned)(r0 - 5 + 16 * t + lane15) < (unsigned)IMH) ? 1.f : 0.f;
            const f32x4 m0 = mx0 * spl4(rr);
            const f32x4 m1 = mx1 * spl4(rr);
            x0 *= m0; x1 *= m1; y0 *= m0; y1 *= m1;
        }

        // L1 (exact f32; output rows = slots 5..68, each counted once) — packed
        {
            const float rmL1 = (t == 0) ? ((lane15 >= 5) ? 1.f : 0.f)
                             : (t == 4) ? ((lane15 <= 4) ? 1.f : 0.f)
                             : 1.f;
            const f32x2 rm2 = spl2(rmL1);
            const f32x2 t0 = abs2(pk_sub(lo2(x0), lo2(y0)));
            const f32x2 t1 = abs2(pk_sub(hi2(x0), hi2(y0)));
            const f32x2 t2 = abs2(pk_sub(lo2(x1), lo2(y1)));
            const f32x2 t3 = abs2(pk_sub(hi2(x1), hi2(y1)));
            const f32x2 s01 = pk_fma(cw0lo, t0, pk_mul(cw1lo, t2));
            const f32x2 s23 = pk_fma(cw0hi, t1, pk_mul(cw1hi, t3));
            l1a = pk_fma(s01, rm2, l1a);
            l1b = pk_fma(s23, rm2, l1b);
        }

        // quantity products — packed
        const f32x2 q2al = pk_fma(lo2(x0), lo2(x0), pk_mul(lo2(y0), lo2(y0)));
        const f32x2 q2ah = pk_fma(hi2(x0), hi2(x0), pk_mul(hi2(y0), hi2(y0)));
        const f32x2 q2bl = pk_fma(lo2(x1), lo2(x1), pk_mul(lo2(y1), lo2(y1)));
        const f32x2 q2bh = pk_fma(hi2(x1), hi2(x1), pk_mul(hi2(y1), hi2(y1)));
        const f32x2 q3al = pk_mul(lo2(x0), lo2(y0));
        const f32x2 q3ah = pk_mul(hi2(x0), hi2(y0));
        const f32x2 q3bl = pk_mul(lo2(x1), lo2(y1));
        const f32x2 q3bh = pk_mul(hi2(x1), hi2(y1));

        uint4 A0u, A1u, A2u, A3u;
        A0u.x = cvtpk(x0[0], x0[1]); A0u.y = cvtpk(x0[2], x0[3]);
        A0u.z = cvtpk(x1[0], x1[1]); A0u.w = cvtpk(x1[2], x1[3]);
        A1u.x = cvtpk(y0[0], y0[1]); A1u.y = cvtpk(y0[2], y0[3]);
        A1u.z = cvtpk(y1[0], y1[1]); A1u.w = cvtpk(y1[2], y1[3]);
        A2u.x = cvtpk(q2al[0], q2al[1]); A2u.y = cvtpk(q2ah[0], q2ah[1]);
        A2u.z = cvtpk(q2bl[0], q2bl[1]); A2u.w = cvtpk(q2bh[0], q2bh[1]);
        A3u.x = cvtpk(q3al[0], q3al[1]); A3u.y = cvtpk(q3ah[0], q3ah[1]);
        A3u.z = cvtpk(q3bl[0], q3bl[1]); A3u.w = cvtpk(q3bh[0], q3bh[1]);

        const s16x8 A0 = __builtin_bit_cast(s16x8, A0u);
        const s16x8 A1 = __builtin_bit_cast(s16x8, A1u);
        const s16x8 A2 = __builtin_bit_cast(s16x8, A2u);
        const s16x8 A3 = __builtin_bit_cast(s16x8, A3u);

        f32x4 C0 = spl4(0.f), C1 = spl4(0.f), C2 = spl4(0.f), C3 = spl4(0.f);
        __builtin_amdgcn_s_setprio(1);
        C0 = __builtin_amdgcn_mfma_f32_16x16x32_bf16(A0, BwH, C0, 0, 0, 0);
        C0 = __builtin_amdgcn_mfma_f32_16x16x32_bf16(A0, BwL, C0, 0, 0, 0);
        C1 = __builtin_amdgcn_mfma_f32_16x16x32_bf16(A1, BwH, C1, 0, 0, 0);
        C1 = __builtin_amdgcn_mfma_f32_16x16x32_bf16(A1, BwL, C1, 0, 0, 0);
        C2 = __builtin_amdgcn_mfma_f32_16x16x32_bf16(A2, BwH, C2, 0, 0, 0);
        C2 = __builtin_amdgcn_mfma_f32_16x16x32_bf16(A2, BwL, C2, 0, 0, 0);
        C3 = __builtin_amdgcn_mfma_f32_16x16x32_bf16(A3, BwH, C3, 0, 0, 0);
        C3 = __builtin_amdgcn_mfma_f32_16x16x32_bf16(A3, BwL, C3, 0, 0, 0);
        __builtin_amdgcn_s_setprio(0);

        // repack band t into rolling H2 slot (t&1)  [wave-private]
        #pragma unroll
        for (int q = 0; q < 4; ++q) {
            const f32x4 Cq = (q == 0) ? C0 : (q == 1) ? C1 : (q == 2) ? C2 : C3;
            uint2 pp;
            pp.x = cvtpk(Cq[0], Cq[1]);
            pp.y = cvtpk(Cq[2], Cq[3]);
            *(uint2*)&LDSU[H2B + ((wv * 4 + q) * 16 + lane15) * H2P2 + (t & 1) * 8 + 2 * g] = pp;
        }

        // v-pass for output tile t-1 (needs bands t-1 and t) [wave-private]
        if (t >= 1) VPASS(t - 1);
    }

    // ---- reductions (single final barrier of the kernel) ----
    float l1sum = (l1a[0] + l1a[1]) + (l1b[0] + l1b[1]);
    float ssum  = (ssa[0] + ssa[1]) + (ssb[0] + ssb[1]);
    #pragma unroll
    for (int off = 32; off > 0; off >>= 1) {
        l1sum += __shfl_down(l1sum, off);
        ssum  += __shfl_down(ssum,  off);
    }
    float* red = (float*)&LDSU[13312];
    if (lane == 0) { red[wv] = l1sum; red[4 + wv] = ssum; }
    __syncthreads();
    if (tid == 0) {
        const float L1 = red[0] + red[1] + red[2] + red[3];
        const float SS = red[4] + red[5] + red[6] + red[7];
        const int bid = (blockIdx.z * gridDim.y + blockIdx.y) * gridDim.x + blockIdx.x;
        partial[bid] = make_float2(L1, SS);
    }
}

__global__ __launch_bounds__(256)
void reduce_kernel(const float2* __restrict__ partial, float* __restrict__ out)
{
    double l1 = 0.0, ss = 0.0;
    for (int i = threadIdx.x; i < NBLK; i += 256) {
        const float2 p = partial[i];
        l1 += (double)p.x;
        ss += (double)p.y;
    }
    #pragma unroll
    for (int off = 32; off > 0; off >>= 1) {
        l1 += __shfl_down(l1, off);
        ss += __shfl_down(ss, off);
    }
    __shared__ double red[8];
    const int wv = threadIdx.x >> 6, lane = threadIdx.x & 63;
    if (lane == 0) { red[wv] = l1; red[4 + wv] = ss; }
    __syncthreads();
    if (threadIdx.x == 0) {
        const double n = 25165824.0;   // 32*3*512*512
        const double L1 = (red[0] + red[1] + red[2] + red[3]) / n;
        const double SS = (red[4] + red[5] + red[6] + red[7]) / n;
        out[0] = (float)(0.5 * L1 + 0.5 * (1.0 - SS));
    }
}

extern "C" void kernel_launch(void* const* d_in, const int* in_sizes, int n_in,
                              void* d_out, int out_size, void* d_ws, size_t ws_size,
                              hipStream_t stream)
{
    const float* warped = (const float*)d_in[0];
    const float* target = (const float*)d_in[1];
    float* out = (float*)d_out;
    uint4* wtab = (uint4*)d_ws;                            // 4 KB fragment table
    float2* partial = (float2*)((char*)d_ws + 4096);       // NBLK float2 partials

    hipLaunchKernelGGL(setup_kernel, dim3(1), dim3(64), 0, stream, wtab);
    hipLaunchKernelGGL(ssim_l1_kernel, dim3(NBX, NBY, 96), dim3(256), 0, stream,
                       warped, target, wtab, partial);
    hipLaunchKernelGGL(reduce_kernel, dim3(1), dim3(256), 0, stream, partial, out);
}